// Round 7
// baseline (396.873 us; speedup 1.0000x reference)
//
#include <hip/hip_runtime.h>
#include <hip/hip_cooperative_groups.h>
#include <hip/hip_bf16.h>
#include <cstddef>

namespace cg = cooperative_groups;

// Problem constants (match reference)
constexpr int NN = 20000;   // nodes
constexpr int NE = 320000;  // edges
constexpr int NHEAD = 4;
constexpr int HD = 512;     // H*D
constexpr int MPAD = 20096; // 314*64 padded rows for GEMM tiles
constexpr int NT = (MPAD / 64) * NHEAD;  // 1256 GEMM tiles
constexpr int SLOTS = 64;   // padded-CSR slots per node (Poisson(16))
constexpr float NEG_SLOPE = 0.2f;

using short8 = __attribute__((ext_vector_type(8))) short;
using f32x4 = __attribute__((ext_vector_type(4))) float;

__device__ inline void gload16(const void* g, void* l) {
  __builtin_amdgcn_global_load_lds(
      (const __attribute__((address_space(1))) void*)g,
      (__attribute__((address_space(3))) void*)l, 16, 0, 0);
}

__device__ inline float fastrcp(float x) { return __builtin_amdgcn_rcpf(x); }

__device__ inline float fast_elu(float x) {
  return (x > 0.f) ? x : (__expf(x) - 1.0f);
}

// ---------------- prep segments (R6-identical) ------------------------------
constexpr int S0 = NN;                      // cnt zero
constexpr int S1 = S0 + NN * 128 / 4;       // featsb (4 elems per item)
constexpr int S2 = S1 + 512 * 128;          // W1t
constexpr int S3 = S2 + 4 * 16 * 128;       // vcombh (8192)
constexpr int S4 = S3 + 1024;               // wl1t + wr1t
constexpr int S5 = S4 + 60000;              // elq+er2 zero (NN*12 floats, x4)
constexpr int S6 = S5 + 256;                // partials zero

__device__ __forceinline__ void dev_prep_item(
    int t, const float* feats, const float* W1, const float* W2,
    const float* al1, const float* ar1, const float* al2, const float* ar2,
    const float* Wr, __hip_bfloat16* featsb, __hip_bfloat16* W1t,
    __hip_bfloat16* vcombh, float* wl1t, float* wr1t, float* zero3,
    float* partials, int* cnt) {
  if (t < S0) {
    cnt[t] = 0;
  } else if (t < S1) {
    int u = (t - S0) * 4;
    float4 f = *reinterpret_cast<const float4*>(&feats[u]);
    __hip_bfloat162 o0 = __float22bfloat162_rn(make_float2(f.x, f.y));
    __hip_bfloat162 o1 = __float22bfloat162_rn(make_float2(f.z, f.w));
    uint2 pk;
    pk.x = *reinterpret_cast<unsigned int*>(&o0);
    pk.y = *reinterpret_cast<unsigned int*>(&o1);
    *reinterpret_cast<uint2*>(&featsb[u]) = pk;
  } else if (t < S2) {
    int u = t - S1;                       // W1t[col][k]
    W1t[u] = __float2bfloat16(W1[(size_t)(u & 127) * 512 + (u >> 7)]);
  } else if (t < S3) {
    int u = t - S2;                       // vcombh[head][m][kk], swizzled
    int head = u >> 11, rem = u & 2047;
    int m = rem >> 7, kk = rem & 127;
    float s = 0.f;
    if (m < 12) {
      int h = m & 3;
      const float* vec = (m < 4) ? (al2 + h * 128)
                       : (m < 8) ? (ar2 + h * 128) : Wr;
      const float* wrow = W2 + (size_t)(head * 128 + kk) * 512 + h * 128;
      for (int d = 0; d < 128; ++d) s += wrow[d] * vec[d];
    }
    int slot = kk >> 3, e = kk & 7;
    int sl = slot ^ (m & 7);
    vcombh[head * 2048 + m * 128 + sl * 8 + e] = __float2bfloat16(s);
  } else if (t < S4) {
    int u = t - S3;                       // wl1t/wr1t[d][h]
    int d = u >> 3, rem = u & 7, h = rem >> 1, sel = rem & 1;
    const float* vec = (sel ? ar1 : al1) + h * 128;
    const float* wrow = W1 + (size_t)d * 512 + h * 128;
    float s = 0.f;
    for (int dd = 0; dd < 128; ++dd) s += wrow[dd] * vec[dd];
    (sel ? wr1t : wl1t)[d * 4 + h] = s;
  } else if (t < S5) {
    int u = (t - S4) * 4;                 // elq + er2 contiguous zero
    *reinterpret_cast<float4*>(&zero3[u]) = make_float4(0.f, 0.f, 0.f, 0.f);
  } else if (t < S6) {
    partials[t - S5] = 0.f;
  }
}

// ---------------- CSR fill (one edge) ---------------------------------------
__device__ __forceinline__ void dev_fill_edge(
    int e, const int* src, const int* dst, int* cnt, int* src_perm) {
  int d = dst[e];
  int p = atomicAdd(&cnt[d], 1);
  if (p < SLOTS) src_perm[d * SLOTS + p] = src[e];
}

// ---------------- layer-1 logits (one node-wave) ----------------------------
__device__ __forceinline__ void dev_logits_node(
    int n, int lane, const __hip_bfloat16* featsb, const float* wl1t,
    const float* wr1t, float* el1, float* er1) {
  unsigned int uu = *reinterpret_cast<const unsigned int*>(
      &featsb[(size_t)n * 128 + 2 * lane]);
  __hip_bfloat162 ub = *reinterpret_cast<__hip_bfloat162*>(&uu);
  float2 f = __bfloat1622float2(ub);
  float4 wlA = *reinterpret_cast<const float4*>(&wl1t[lane * 8]);
  float4 wlB = *reinterpret_cast<const float4*>(&wl1t[lane * 8 + 4]);
  float4 wrA = *reinterpret_cast<const float4*>(&wr1t[lane * 8]);
  float4 wrB = *reinterpret_cast<const float4*>(&wr1t[lane * 8 + 4]);
  float p0 = f.x * wlA.x + f.y * wlB.x;
  float p1 = f.x * wlA.y + f.y * wlB.y;
  float p2 = f.x * wlA.z + f.y * wlB.z;
  float p3 = f.x * wlA.w + f.y * wlB.w;
  float p4 = f.x * wrA.x + f.y * wrB.x;
  float p5 = f.x * wrA.y + f.y * wrB.y;
  float p6 = f.x * wrA.z + f.y * wrB.z;
  float p7 = f.x * wrA.w + f.y * wrB.w;
#pragma unroll
  for (int off = 1; off < 64; off <<= 1) {
    p0 += __shfl_xor(p0, off); p1 += __shfl_xor(p1, off);
    p2 += __shfl_xor(p2, off); p3 += __shfl_xor(p3, off);
    p4 += __shfl_xor(p4, off); p5 += __shfl_xor(p5, off);
    p6 += __shfl_xor(p6, off); p7 += __shfl_xor(p7, off);
  }
  if (lane == 0) {
    *reinterpret_cast<float4*>(&el1[n * 4]) = make_float4(p0, p1, p2, p3);
    *reinterpret_cast<float4*>(&er1[n * 4]) = make_float4(p4, p5, p6, p7);
  }
}

// ---------------- gather (one node-wave) ------------------------------------
__device__ __forceinline__ void dev_gather_node(
    int n, int lane, float4* alphW, int* srcbW,
    const __hip_bfloat16* featsb, const int* cnt, const int* src_perm,
    const float* el, const float* er, __hip_bfloat16* aggb) {
  int c = min(cnt[n], SLOTS);
  {
    float4 er4 = *reinterpret_cast<const float4*>(&er[n * 4]);
    float a0 = 0.f, a1 = 0.f, a2 = 0.f, a3 = 0.f;
    int sv = 0;
    if (lane < c) {
      sv = src_perm[n * SLOTS + lane];
      float4 e4 = *reinterpret_cast<const float4*>(&el[sv * 4]);
      float x0 = e4.x + er4.x, x1 = e4.y + er4.y;
      float x2 = e4.z + er4.z, x3 = e4.w + er4.w;
      x0 = (x0 > 0.f) ? x0 : NEG_SLOPE * x0;
      x1 = (x1 > 0.f) ? x1 : NEG_SLOPE * x1;
      x2 = (x2 > 0.f) ? x2 : NEG_SLOPE * x2;
      x3 = (x3 > 0.f) ? x3 : NEG_SLOPE * x3;
      a0 = __expf(x0); a1 = __expf(x1); a2 = __expf(x2); a3 = __expf(x3);
    }
    float s0 = a0, s1 = a1, s2 = a2, s3 = a3;
#pragma unroll
    for (int off = 1; off < 64; off <<= 1) {
      s0 += __shfl_xor(s0, off);
      s1 += __shfl_xor(s1, off);
      s2 += __shfl_xor(s2, off);
      s3 += __shfl_xor(s3, off);
    }
    float i0 = fastrcp(fmaxf(s0, 1e-9f));
    float i1 = fastrcp(fmaxf(s1, 1e-9f));
    float i2 = fastrcp(fmaxf(s2, 1e-9f));
    float i3 = fastrcp(fmaxf(s3, 1e-9f));
    alphW[lane] = make_float4(a0 * i0, a1 * i1, a2 * i2, a3 * i3);
    srcbW[lane] = sv;   // same-wave producer/consumer, no barrier
  }

  float acc[4][2] = {};
#define EB(IDX)                                                                \
  {                                                                            \
    float4 a4 = alphW[(IDX)];                                                  \
    int s = srcbW[(IDX)];                                                      \
    unsigned int uu = *reinterpret_cast<const unsigned int*>(                  \
        &featsb[(size_t)s * 128 + 2 * lane]);                                  \
    __hip_bfloat162 ub = *reinterpret_cast<__hip_bfloat162*>(&uu);             \
    float2 f = __bfloat1622float2(ub);                                         \
    acc[0][0] += a4.x * f.x; acc[0][1] += a4.x * f.y;                          \
    acc[1][0] += a4.y * f.x; acc[1][1] += a4.y * f.y;                          \
    acc[2][0] += a4.z * f.x; acc[2][1] += a4.z * f.y;                          \
    acc[3][0] += a4.w * f.x; acc[3][1] += a4.w * f.y;                          \
  }
  int i = 0;
  for (; i + 3 < c; i += 4) { EB(i) EB(i + 1) EB(i + 2) EB(i + 3) }
  for (; i < c; ++i) EB(i)
#undef EB

  size_t obase = (size_t)n * HD + 2 * lane;
#pragma unroll
  for (int h = 0; h < 4; ++h) {
    __hip_bfloat162 o = __float22bfloat162_rn(make_float2(acc[h][0], acc[h][1]));
    *reinterpret_cast<unsigned int*>(&aggb[obase + h * 128]) =
        *reinterpret_cast<unsigned int*>(&o);
  }
}

// ---------------- h1 GEMM pieces --------------------------------------------
__device__ __forceinline__ void dev_stage_BV(
    int head, int lane, int wave, short* Bs, short* Vc,
    const __hip_bfloat16* Bt, const __hip_bfloat16* vcombh) {
#pragma unroll
  for (int p = 0; p < 8; ++p) {             // B: 128 rows x 16 slots
    int fbase = p * 256 + wave * 64;
    int f = fbase + lane;
    int row = f >> 4, slot = f & 15;
    int ss = slot ^ (row & 7);
    gload16(Bt + (size_t)(head * 128 + row) * 128 + ss * 8, Bs + fbase * 8);
  }
  {
    int fbase = wave * 64;                  // Vc: pre-swizzled in global
    gload16(vcombh + head * 2048 + (size_t)(fbase + lane) * 8, Vc + fbase * 8);
  }
}

__device__ __forceinline__ void dev_stage_A(
    int rowBase, int head, int lane, int wave, short* AsH,
    const __hip_bfloat16* A) {
#pragma unroll
  for (int p = 0; p < 4; ++p) {             // A: 64 rows x 16 slots
    int fbase = p * 256 + wave * 64;
    int f = fbase + lane;
    int row = f >> 4, slot = f & 15;
    int ss = slot ^ (row & 7);
    gload16(A + (size_t)(rowBase + row) * HD + head * 128 + ss * 8,
            AsH + fbase * 8);
  }
}

__device__ __forceinline__ void dev_h1_compute(
    int rowBase, int head, int lane, int wave, short* AsH, const short* Bs,
    const short* Vc, const float* b1, float* elq, float* er2) {
  int nloc = lane & 15, quad = lane >> 4;

  f32x4 acc[8];
#pragma unroll
  for (int i = 0; i < 8; ++i) acc[i] = (f32x4){0.f, 0.f, 0.f, 0.f};
#pragma unroll
  for (int c = 0; c < 4; ++c) {
    int arow = wave * 16 + nloc;
    short8 bfr = *(const short8*)&AsH[arow * 128 +
                                      (((c << 2) + quad) ^ (arow & 7)) * 8];
#pragma unroll
    for (int i = 0; i < 8; ++i) {
      int brow = i * 16 + nloc;
      short8 af = *(const short8*)&Bs[brow * 128 +
                                      (((c << 2) + quad) ^ (brow & 7)) * 8];
      acc[i] = __builtin_amdgcn_mfma_f32_16x16x32_bf16(af, bfr, acc[i], 0, 0, 0);
    }
  }

  int node = wave * 16 + nloc;
#pragma unroll
  for (int i = 0; i < 8; ++i) {
    float4 b4 = *reinterpret_cast<const float4*>(
        &b1[head * 128 + i * 16 + quad * 4]);
    float e0 = fast_elu(acc[i][0] + b4.x);
    float e1 = fast_elu(acc[i][1] + b4.y);
    float e2 = fast_elu(acc[i][2] + b4.z);
    float e3 = fast_elu(acc[i][3] + b4.w);
    __hip_bfloat162 p0 = __float22bfloat162_rn(make_float2(e0, e1));
    __hip_bfloat162 p1 = __float22bfloat162_rn(make_float2(e2, e3));
    uint2 pk;
    pk.x = *reinterpret_cast<unsigned int*>(&p0);
    pk.y = *reinterpret_cast<unsigned int*>(&p1);
    int slot = i * 2 + (quad >> 1);
    int sub = quad & 1;
    int sl = slot ^ (node & 7);
    *reinterpret_cast<uint2*>(&AsH[node * 128 + sl * 8 + sub * 4]) = pk;
  }

  f32x4 acc2 = (f32x4){0.f, 0.f, 0.f, 0.f};
#pragma unroll
  for (int c = 0; c < 4; ++c) {
    short8 a2 = *(const short8*)&Vc[nloc * 128 +
                                    (((c << 2) + quad) ^ (nloc & 7)) * 8];
    short8 b2v = *(const short8*)&AsH[node * 128 +
                                      (((c << 2) + quad) ^ (node & 7)) * 8];
    acc2 = __builtin_amdgcn_mfma_f32_16x16x32_bf16(a2, b2v, acc2, 0, 0, 0);
  }

  int gn = rowBase + node;
  if (gn < NN) {
    if (quad == 0) {
#pragma unroll
      for (int r = 0; r < 4; ++r)
        atomicAdd(&elq[(size_t)gn * 8 + r], acc2[r]);
    } else if (quad == 1) {
#pragma unroll
      for (int r = 0; r < 4; ++r)
        atomicAdd(&er2[(size_t)gn * 4 + r], acc2[r]);
    } else if (quad == 2) {
#pragma unroll
      for (int r = 0; r < 4; ++r)
        atomicAdd(&elq[(size_t)gn * 8 + 4 + r], acc2[r]);
    }
  }
}

// ---------------- layer-2 attention (one node-wave) -------------------------
__device__ __forceinline__ float dev_attn_node(
    int n, int lane, const int* src_perm, const int* cnt,
    const float* elq, const float* er2) {
  int c = min(cnt[n], SLOTS);
  float4 er4 = *reinterpret_cast<const float4*>(&er2[n * 4]);
  float a0 = 0.f, a1 = 0.f, a2 = 0.f, a3 = 0.f;
  float4 q4 = make_float4(0.f, 0.f, 0.f, 0.f);
  if (lane < c) {
    int s = src_perm[n * SLOTS + lane];
    float4 e4 = *reinterpret_cast<const float4*>(&elq[(size_t)s * 8]);
    q4 = *reinterpret_cast<const float4*>(&elq[(size_t)s * 8 + 4]);
    float x0 = e4.x + er4.x, x1 = e4.y + er4.y;
    float x2 = e4.z + er4.z, x3 = e4.w + er4.w;
    x0 = (x0 > 0.f) ? x0 : NEG_SLOPE * x0;
    x1 = (x1 > 0.f) ? x1 : NEG_SLOPE * x1;
    x2 = (x2 > 0.f) ? x2 : NEG_SLOPE * x2;
    x3 = (x3 > 0.f) ? x3 : NEG_SLOPE * x3;
    a0 = __expf(x0); a1 = __expf(x1); a2 = __expf(x2); a3 = __expf(x3);
  }
  float s0 = a0, s1 = a1, s2 = a2, s3 = a3;
#pragma unroll
  for (int off = 1; off < 64; off <<= 1) {
    s0 += __shfl_xor(s0, off);
    s1 += __shfl_xor(s1, off);
    s2 += __shfl_xor(s2, off);
    s3 += __shfl_xor(s3, off);
  }
  float p = 0.f;
  if (lane < c) {
    p = (a0 * fastrcp(fmaxf(s0, 1e-9f))) * q4.x +
        (a1 * fastrcp(fmaxf(s1, 1e-9f))) * q4.y +
        (a2 * fastrcp(fmaxf(s2, 1e-9f))) * q4.z +
        (a3 * fastrcp(fmaxf(s3, 1e-9f))) * q4.w;
  }
#pragma unroll
  for (int off = 32; off > 0; off >>= 1) p += __shfl_down(p, off);
  return p;  // valid at lane 0
}

// ---------------- MEGA cooperative kernel -----------------------------------
// R6 insight: three radically different pipelines all plateau at ~167us while
// per-kernel work models sum to ~55us -> the floor is per-dispatch overhead +
// serialization, not work.  Fuse all 6 dispatches into ONE cooperative kernel
// with grid.sync() phase barriers.  LDS 57KB -> 2 blocks/CU; grid sized by
// occupancy query (multiple of 4 so head = bid&3 is constant and W1t/Vc are
// staged once per block).
struct MegaSmem {
  short AsH[64 * 128];        // 16 KB
  short Bs[128 * 128];        // 32 KB
  short Vc[16 * 128];         // 4 KB
  float4 alph[4][SLOTS];      // 4 KB
  int srcb[4][SLOTS];         // 1 KB
  float blk[4];
};

__global__ __launch_bounds__(256, 2) void mega_kernel(
    const float* __restrict__ feats, const float* __restrict__ W1,
    const float* __restrict__ W2, const float* __restrict__ al1,
    const float* __restrict__ ar1, const float* __restrict__ al2,
    const float* __restrict__ ar2, const float* __restrict__ Wr,
    const float* __restrict__ b1, const float* __restrict__ b2,
    const float* __restrict__ br, const int* __restrict__ src,
    const int* __restrict__ dst, __hip_bfloat16* __restrict__ featsb,
    __hip_bfloat16* __restrict__ W1t, __hip_bfloat16* __restrict__ vcombh,
    float* __restrict__ wl1t, float* __restrict__ wr1t,
    float* __restrict__ el1, float* __restrict__ er1,
    __hip_bfloat16* __restrict__ aggb, float* __restrict__ elq,
    float* __restrict__ er2, float* __restrict__ partials,
    int* __restrict__ cnt, int* __restrict__ src_perm,
    float* __restrict__ out) {
  cg::grid_group grid = cg::this_grid();
  __shared__ MegaSmem sm;
  const int t = threadIdx.x;
  const int lane = t & 63, wv = t >> 6;
  const int bid = blockIdx.x, nb = gridDim.x;
  const int gtid = bid * 256 + t, nthr = nb * 256;
  const int gwave = bid * 4 + wv, nwaves = nb * 4;

  // ---- phase 0: prep (cnt zero, featsb, W1t, vcombh, wl1t/wr1t, zeros) ----
  for (int u = gtid; u < S6; u += nthr)
    dev_prep_item(u, feats, W1, W2, al1, ar1, al2, ar2, Wr, featsb, W1t,
                  vcombh, wl1t, wr1t, elq, partials, cnt);
  grid.sync();

  // ---- phase 1: CSR fill + layer-1 logits ----
  for (int e = gtid; e < NE; e += nthr)
    dev_fill_edge(e, src, dst, cnt, src_perm);
  for (int n = gwave; n < NN; n += nwaves)
    dev_logits_node(n, lane, featsb, wl1t, wr1t, el1, er1);
  grid.sync();

  // ---- phase 2: layer-1 attn + feats aggregation ----
  {
    float4* alphW = &sm.alph[wv][0];
    int* srcbW = &sm.srcb[wv][0];
    for (int n = gwave; n < NN; n += nwaves)
      dev_gather_node(n, lane, alphW, srcbW, featsb, cnt, src_perm, el1, er1,
                      aggb);
  }
  grid.sync();

  // ---- phase 3: h1 GEMM + MFMA 12-dot epilogue (head constant per block) ----
  {
    int head = bid & 3;
    dev_stage_BV(head, lane, wv, sm.Bs, sm.Vc, W1t, vcombh);
    for (int tile = bid; tile < NT; tile += nb) {
      int rowBase = (tile >> 2) * 64;
      __syncthreads();   // prior tile's LDS readers done (and BV drained below)
      dev_stage_A(rowBase, head, lane, wv, sm.AsH, aggb);
      __syncthreads();   // all staging (incl BV on first iter) complete
      dev_h1_compute(rowBase, head, lane, wv, sm.AsH, sm.Bs, sm.Vc, b1, elq,
                     er2);
    }
  }
  grid.sync();

  // ---- phase 4: layer-2 attention + readout dot ----
  {
    float wsum = 0.f;
    for (int n = gwave; n < NN; n += nwaves)
      wsum += dev_attn_node(n, lane, src_perm, cnt, elq, er2);
    if (lane == 0) sm.blk[wv] = wsum;
    __syncthreads();
    if (t == 0)
      atomicAdd(&partials[bid & 255],
                sm.blk[0] + sm.blk[1] + sm.blk[2] + sm.blk[3]);
  }
  grid.sync();

  // ---- phase 5: final reduce (block 0) ----
  if (bid == 0) {
    float* tmp = reinterpret_cast<float*>(&sm.alph[0][0]);
    float sum = partials[t] +
                (float)NN * Wr[t & 127] * (b2[t] + b2[t + 256]);
    tmp[t] = sum;
    __syncthreads();
    for (int off = 128; off > 0; off >>= 1) {
      if (t < off) tmp[t] += tmp[t + off];
      __syncthreads();
    }
    if (t == 0) out[0] = 0.25f * tmp[0] + (float)NN * br[0];
  }
}

// ================= fallback path: R6's 6-dispatch pipeline ===================
__global__ __launch_bounds__(256) void prep_kernel(
    const float* __restrict__ feats, const float* __restrict__ W1,
    const float* __restrict__ W2, const float* __restrict__ al1,
    const float* __restrict__ ar1, const float* __restrict__ al2,
    const float* __restrict__ ar2, const float* __restrict__ Wr,
    __hip_bfloat16* __restrict__ featsb, __hip_bfloat16* __restrict__ W1t,
    __hip_bfloat16* __restrict__ vcombh, float* __restrict__ wl1t,
    float* __restrict__ wr1t, float* __restrict__ zero3,
    float* __restrict__ partials, int* __restrict__ cnt) {
  int t = blockIdx.x * 256 + threadIdx.x;
  dev_prep_item(t, feats, W1, W2, al1, ar1, al2, ar2, Wr, featsb, W1t, vcombh,
                wl1t, wr1t, zero3, partials, cnt);
}

__global__ __launch_bounds__(256) void fill_logits_kernel(
    const int* __restrict__ src, const int* __restrict__ dst,
    int* __restrict__ cnt, int* __restrict__ src_perm,
    const __hip_bfloat16* __restrict__ featsb,
    const float* __restrict__ wl1t, const float* __restrict__ wr1t,
    float* __restrict__ el1, float* __restrict__ er1) {
  int t = threadIdx.x;
  int nth = gridDim.x * 256;
  int gid = blockIdx.x * 256 + t;
  for (int e = gid; e < NE; e += nth) dev_fill_edge(e, src, dst, cnt, src_perm);
  int wv = t >> 6, lane = t & 63;
  int n = blockIdx.x * 4 + wv;
  dev_logits_node(n, lane, featsb, wl1t, wr1t, el1, er1);
}

__global__ __launch_bounds__(256) void gather_kernel(
    const __hip_bfloat16* __restrict__ featsb, const int* __restrict__ cnt,
    const int* __restrict__ src_perm, const float* __restrict__ el,
    const float* __restrict__ er, __hip_bfloat16* __restrict__ aggb) {
  __shared__ float4 alph[4][SLOTS];
  __shared__ int srcb[4][SLOTS];
  int wv = __builtin_amdgcn_readfirstlane((int)(threadIdx.x >> 6));
  int n = blockIdx.x * 4 + wv;
  int lane = threadIdx.x & 63;
  dev_gather_node(n, lane, &alph[wv][0], &srcb[wv][0], featsb, cnt, src_perm,
                  el, er, aggb);
}

__global__ __launch_bounds__(256) void h1_gemm_kernel(
    const __hip_bfloat16* __restrict__ A, const __hip_bfloat16* __restrict__ Bt,
    const __hip_bfloat16* __restrict__ vcombh, const float* __restrict__ b1,
    float* __restrict__ elq, float* __restrict__ er2) {
  __shared__ short AsH[64 * 128];
  __shared__ short Bs[128 * 128];
  __shared__ short Vc[16 * 128];
  int t = threadIdx.x;
  int lane = t & 63, wave = t >> 6;
  int rowBase = blockIdx.x * 64;
  int head = blockIdx.y;
  dev_stage_A(rowBase, head, lane, wave, AsH, A);
  dev_stage_BV(head, lane, wave, Bs, Vc, Bt, vcombh);
  __syncthreads();
  dev_h1_compute(rowBase, head, lane, wave, AsH, Bs, Vc, b1, elq, er2);
}

__global__ __launch_bounds__(256) void attn_q_kernel(
    const int* __restrict__ src_perm, const int* __restrict__ cnt,
    const float* __restrict__ elq, const float* __restrict__ er2,
    float* __restrict__ partials) {
  __shared__ float blk[4];
  int wv = __builtin_amdgcn_readfirstlane((int)(threadIdx.x >> 6));
  int n = blockIdx.x * 4 + wv;
  int lane = threadIdx.x & 63;
  float p = dev_attn_node(n, lane, src_perm, cnt, elq, er2);
  if (lane == 0) blk[wv] = p;
  __syncthreads();
  if (threadIdx.x == 0)
    atomicAdd(&partials[blockIdx.x & 255], blk[0] + blk[1] + blk[2] + blk[3]);
}

__global__ __launch_bounds__(512) void final_kernel(
    const float* __restrict__ partials, const float* __restrict__ b2,
    const float* __restrict__ Wr, const float* __restrict__ br,
    float* __restrict__ out) {
  __shared__ float tmp[512];
  int t = threadIdx.x;
  float sum = (t < 256) ? partials[t] : 0.f;
  sum += (float)NN * b2[t] * Wr[t & 127];
  tmp[t] = sum;
  __syncthreads();
  for (int off = 256; off > 0; off >>= 1) {
    if (t < off) tmp[t] += tmp[t + off];
    __syncthreads();
  }
  if (t == 0) out[0] = 0.25f * tmp[0] + (float)NN * br[0];
}

// ---------------- launch ----------------
extern "C" void kernel_launch(void* const* d_in, const int* in_sizes, int n_in,
                              void* d_out, int out_size, void* d_ws, size_t ws_size,
                              hipStream_t stream) {
  const float* feats = (const float*)d_in[0];
  const int* src = (const int*)d_in[1];
  const int* dst = (const int*)d_in[2];
  const float* W1 = (const float*)d_in[3];
  const float* al1 = (const float*)d_in[4];
  const float* ar1 = (const float*)d_in[5];
  const float* b1 = (const float*)d_in[6];
  const float* W2 = (const float*)d_in[7];
  const float* al2 = (const float*)d_in[8];
  const float* ar2 = (const float*)d_in[9];
  const float* b2 = (const float*)d_in[10];
  const float* Wr = (const float*)d_in[11];
  const float* br = (const float*)d_in[12];
  float* out = (float*)d_out;

  // workspace layout (~33 MB); all section sizes multiples of 16 B
  __hip_bfloat16* featsb = (__hip_bfloat16*)d_ws;               // NN*128 bf16
  __hip_bfloat16* aggb = featsb + (size_t)NN * 128;             // MPAD*512 bf16
  __hip_bfloat16* W1t = aggb + (size_t)MPAD * HD;               // 512*128 bf16
  __hip_bfloat16* vcombh = W1t + 512 * 128;                     // 4*16*128 bf16
  float* wl1t = (float*)(vcombh + 4 * 16 * 128);                // 128*4 f32
  float* wr1t = wl1t + 512;                                     // 128*4 f32
  float* el1 = wr1t + 512;                                      // NN*4
  float* er1 = el1 + (size_t)NN * NHEAD;                        // NN*4
  float* elq = er1 + (size_t)NN * NHEAD;                        // NN*8
  float* er2 = elq + (size_t)NN * 8;                            // NN*4
  float* partials = er2 + (size_t)NN * NHEAD;                   // 256
  int* cnt = (int*)(partials + 256);                            // NN
  int* src_perm = cnt + NN;                                     // NN*SLOTS

  // cooperative grid size: occupancy-derived, multiple of 4, conservative
  static int gridX = -1;
  if (gridX < 0) {
    int nbPerCU = 0;
    hipError_t qe = hipOccupancyMaxActiveBlocksPerMultiprocessor(
        &nbPerCU, (const void*)mega_kernel, 256, 0);
    if (qe != hipSuccess || nbPerCU < 1) nbPerCU = 0;
    int g = nbPerCU * 256;       // 256 CUs on MI355X
    if (g > 1024) g = 1024;
    g &= ~3;                     // head = bid & 3 constant per block
    gridX = (g >= 4) ? g : 0;    // 0 => fallback path
  }

  bool coop_ok = false;
  if (gridX > 0) {
    void* args[] = {
        (void*)&feats, (void*)&W1,  (void*)&W2,  (void*)&al1, (void*)&ar1,
        (void*)&al2,   (void*)&ar2, (void*)&Wr,  (void*)&b1,  (void*)&b2,
        (void*)&br,    (void*)&src, (void*)&dst, (void*)&featsb,
        (void*)&W1t,   (void*)&vcombh, (void*)&wl1t, (void*)&wr1t,
        (void*)&el1,   (void*)&er1, (void*)&aggb, (void*)&elq, (void*)&er2,
        (void*)&partials, (void*)&cnt, (void*)&src_perm, (void*)&out};
    hipError_t le = hipLaunchCooperativeKernel(
        reinterpret_cast<void*>(mega_kernel), dim3(gridX), dim3(256), args, 0,
        stream);
    coop_ok = (le == hipSuccess);
    if (!coop_ok) gridX = 0;   // don't retry every call
  }

  if (!coop_ok) {
    // R6-proven 6-dispatch fallback
    prep_kernel<<<(S6 + 255) / 256, 256, 0, stream>>>(
        feats, W1, W2, al1, ar1, al2, ar2, Wr, featsb, W1t, vcombh, wl1t,
        wr1t, elq, partials, cnt);
    fill_logits_kernel<<<NN / 4, 256, 0, stream>>>(
        src, dst, cnt, src_perm, featsb, wl1t, wr1t, el1, er1);
    gather_kernel<<<NN / 4, 256, 0, stream>>>(featsb, cnt, src_perm, el1, er1,
                                              aggb);
    dim3 h1grid(MPAD / 64, NHEAD);
    h1_gemm_kernel<<<h1grid, 256, 0, stream>>>(aggb, W1t, vcombh, b1, elq,
                                               er2);
    attn_q_kernel<<<NN / 4, 256, 0, stream>>>(src_perm, cnt, elq, er2,
                                              partials);
    final_kernel<<<1, 512, 0, stream>>>(partials, b2, Wr, br, out);
  }
}

// Round 8
// 173.920 us; speedup vs baseline: 2.2819x; 2.2819x over previous
//
#include <hip/hip_runtime.h>
#include <hip/hip_bf16.h>
#include <cstddef>

// Problem constants (match reference)
constexpr int NN = 20000;   // nodes
constexpr int NE = 320000;  // edges
constexpr int NHEAD = 4;
constexpr int HD = 512;     // H*D
constexpr int MPAD = 20096; // 314*64 padded rows for GEMM tiles
constexpr int SLOTS = 64;   // padded-CSR slots per node (Poisson(16))
constexpr float NEG_SLOPE = 0.2f;

using short8 = __attribute__((ext_vector_type(8))) short;
using f32x4 = __attribute__((ext_vector_type(4))) float;

// async global->LDS, 16B per lane, LDS dest = wave-uniform base + lane*16
__device__ inline void gload16(const void* g, void* l) {
  __builtin_amdgcn_global_load_lds(
      (const __attribute__((address_space(1))) void*)g,
      (__attribute__((address_space(3))) void*)l, 16, 0, 0);
}

__device__ inline float fastrcp(float x) { return __builtin_amdgcn_rcpf(x); }

// fast ELU negative branch: 3-inst vs ~30-inst expm1f
__device__ inline float fast_elu(float x) {
  return (x > 0.f) ? x : (__expf(x) - 1.0f);
}

// ---------------- fused prep (R6-identical) ----------------------------------
constexpr int S0 = NN;                      // cnt zero
constexpr int S1 = S0 + NN * 128 / 4;       // featsb (4 elems per item)
constexpr int S2 = S1 + 512 * 128;          // W1t
constexpr int S3 = S2 + 4 * 16 * 128;       // vcombh (8192)
constexpr int S4 = S3 + 1024;               // wl1t + wr1t (128*4 each)
constexpr int S5 = S4 + 60000;              // elq+er2 zero (NN*12 floats, x4)
constexpr int S6 = S5 + 256;                // partials zero
__global__ __launch_bounds__(256) void prep_kernel(
    const float* __restrict__ feats, const float* __restrict__ W1,
    const float* __restrict__ W2, const float* __restrict__ al1,
    const float* __restrict__ ar1, const float* __restrict__ al2,
    const float* __restrict__ ar2, const float* __restrict__ Wr,
    __hip_bfloat16* __restrict__ featsb, __hip_bfloat16* __restrict__ W1t,
    __hip_bfloat16* __restrict__ vcombh, float* __restrict__ wl1t,
    float* __restrict__ wr1t, float* __restrict__ zero3,
    float* __restrict__ partials, int* __restrict__ cnt) {
  int t = blockIdx.x * 256 + threadIdx.x;
  if (t < S0) {
    cnt[t] = 0;
  } else if (t < S1) {
    int u = (t - S0) * 4;
    float4 f = *reinterpret_cast<const float4*>(&feats[u]);
    __hip_bfloat162 o0 = __float22bfloat162_rn(make_float2(f.x, f.y));
    __hip_bfloat162 o1 = __float22bfloat162_rn(make_float2(f.z, f.w));
    uint2 pk;
    pk.x = *reinterpret_cast<unsigned int*>(&o0);
    pk.y = *reinterpret_cast<unsigned int*>(&o1);
    *reinterpret_cast<uint2*>(&featsb[u]) = pk;
  } else if (t < S2) {
    int u = t - S1;                       // W1t[col][k]
    W1t[u] = __float2bfloat16(W1[(size_t)(u & 127) * 512 + (u >> 7)]);
  } else if (t < S3) {
    int u = t - S2;                       // vcombh[head][m][kk], swizzled
    int head = u >> 11, rem = u & 2047;
    int m = rem >> 7, kk = rem & 127;
    float s = 0.f;
    if (m < 12) {
      int h = m & 3;
      const float* vec = (m < 4) ? (al2 + h * 128)
                       : (m < 8) ? (ar2 + h * 128) : Wr;
      const float* wrow = W2 + (size_t)(head * 128 + kk) * 512 + h * 128;
      for (int d = 0; d < 128; ++d) s += wrow[d] * vec[d];
    }
    int slot = kk >> 3, e = kk & 7;
    int sl = slot ^ (m & 7);
    vcombh[head * 2048 + m * 128 + sl * 8 + e] = __float2bfloat16(s);
  } else if (t < S4) {
    int u = t - S3;                       // wl1t/wr1t[d][h]
    int d = u >> 3, rem = u & 7, h = rem >> 1, sel = rem & 1;
    const float* vec = (sel ? ar1 : al1) + h * 128;
    const float* wrow = W1 + (size_t)d * 512 + h * 128;
    float s = 0.f;
    for (int dd = 0; dd < 128; ++dd) s += wrow[dd] * vec[dd];
    (sel ? wr1t : wl1t)[d * 4 + h] = s;
  } else if (t < S5) {
    int u = (t - S4) * 4;                 // elq + er2 contiguous zero
    *reinterpret_cast<float4*>(&zero3[u]) = make_float4(0.f, 0.f, 0.f, 0.f);
  } else if (t < S6) {
    partials[t - S5] = 0.f;
  }
}

// ---------------- CSR fill + layer-1 logits ---------------------------------
// Widened loads (G13: 4B bf16 loads cost ~2x): each wave handles TWO nodes,
// half-wave per node, 8B (4 bf16) per lane, 5-level butterfly.
// Grid NN/8 = 2500 blocks; CSR grid-stride covers NE with 640K threads.
__global__ __launch_bounds__(256) void fill_logits_kernel(
    const int* __restrict__ src, const int* __restrict__ dst,
    int* __restrict__ cnt, int* __restrict__ src_perm,
    const __hip_bfloat16* __restrict__ featsb,
    const float* __restrict__ wl1t, const float* __restrict__ wr1t,
    float* __restrict__ el1, float* __restrict__ er1) {
  int t = threadIdx.x;
  {
    int nth = gridDim.x * 256;
    int gid = blockIdx.x * 256 + t;
    for (int e = gid; e < NE; e += nth) {
      int d = dst[e];
      int p = atomicAdd(&cnt[d], 1);
      if (p < SLOTS) src_perm[d * SLOTS + p] = src[e];
    }
  }
  int wv = t >> 6, lane = t & 63;
  int half = lane >> 5, l5 = lane & 31;
  int n = blockIdx.x * 8 + wv * 2 + half;   // 2500*8 = 20000 exact
  int d0 = l5 * 4;
  uint2 w = *reinterpret_cast<const uint2*>(&featsb[(size_t)n * 128 + d0]);
  __hip_bfloat162 u0 = *reinterpret_cast<__hip_bfloat162*>(&w.x);
  __hip_bfloat162 u1 = *reinterpret_cast<__hip_bfloat162*>(&w.y);
  float2 fA = __bfloat1622float2(u0);
  float2 fB = __bfloat1622float2(u1);
  float f[4] = {fA.x, fA.y, fB.x, fB.y};
  float pl[4] = {0.f, 0.f, 0.f, 0.f}, pr[4] = {0.f, 0.f, 0.f, 0.f};
#pragma unroll
  for (int j = 0; j < 4; ++j) {
    float4 wl = *reinterpret_cast<const float4*>(&wl1t[(d0 + j) * 4]);
    float4 wr = *reinterpret_cast<const float4*>(&wr1t[(d0 + j) * 4]);
    pl[0] += f[j] * wl.x; pl[1] += f[j] * wl.y;
    pl[2] += f[j] * wl.z; pl[3] += f[j] * wl.w;
    pr[0] += f[j] * wr.x; pr[1] += f[j] * wr.y;
    pr[2] += f[j] * wr.z; pr[3] += f[j] * wr.w;
  }
#pragma unroll
  for (int off = 1; off < 32; off <<= 1) {
#pragma unroll
    for (int k = 0; k < 4; ++k) {
      pl[k] += __shfl_xor(pl[k], off);
      pr[k] += __shfl_xor(pr[k], off);
    }
  }
  if (l5 == 0) {
    *reinterpret_cast<float4*>(&el1[n * 4]) =
        make_float4(pl[0], pl[1], pl[2], pl[3]);
    *reinterpret_cast<float4*>(&er1[n * 4]) =
        make_float4(pr[0], pr[1], pr[2], pr[3]);
  }
}

// ---------------- layer-1 attention + FEATS aggregation ---------------------
// Phase 1 (lane = slot) unchanged.  Phase 2 widened (G13): half-wave per
// edge, TWO edges per wave-iteration, 8B loads, serial depth 16 -> 8; halves
// combined once at the end via shfl_xor(32).  Slots >= c have alpha == 0 and
// src == 0, so an odd tail edge contributes exactly 0 — no guard needed.
__global__ __launch_bounds__(256) void gather_kernel(
    const __hip_bfloat16* __restrict__ featsb,
    const int* __restrict__ cnt, const int* __restrict__ src_perm,
    const float* __restrict__ el, const float* __restrict__ er,
    __hip_bfloat16* __restrict__ aggb) {         // [MPAD][4*128] bf16
  __shared__ float4 alph[4][SLOTS];
  __shared__ int srcb[4][SLOTS];
  int wv = __builtin_amdgcn_readfirstlane((int)(threadIdx.x >> 6));
  int n = blockIdx.x * 4 + wv;
  int lane = threadIdx.x & 63;
  int c = min(cnt[n], SLOTS);

  // ---- phase 1: attention coefficients (lane = slot) ----
  {
    float4 er4 = *reinterpret_cast<const float4*>(&er[n * 4]);
    float a0 = 0.f, a1 = 0.f, a2 = 0.f, a3 = 0.f;
    int sv = 0;
    if (lane < c) {
      sv = src_perm[n * SLOTS + lane];
      float4 e4 = *reinterpret_cast<const float4*>(&el[sv * 4]);
      float x0 = e4.x + er4.x, x1 = e4.y + er4.y;
      float x2 = e4.z + er4.z, x3 = e4.w + er4.w;
      x0 = (x0 > 0.f) ? x0 : NEG_SLOPE * x0;
      x1 = (x1 > 0.f) ? x1 : NEG_SLOPE * x1;
      x2 = (x2 > 0.f) ? x2 : NEG_SLOPE * x2;
      x3 = (x3 > 0.f) ? x3 : NEG_SLOPE * x3;
      a0 = __expf(x0); a1 = __expf(x1); a2 = __expf(x2); a3 = __expf(x3);
    }
    float s0 = a0, s1 = a1, s2 = a2, s3 = a3;
#pragma unroll
    for (int off = 1; off < 64; off <<= 1) {
      s0 += __shfl_xor(s0, off);
      s1 += __shfl_xor(s1, off);
      s2 += __shfl_xor(s2, off);
      s3 += __shfl_xor(s3, off);
    }
    float i0 = fastrcp(fmaxf(s0, 1e-9f));
    float i1 = fastrcp(fmaxf(s1, 1e-9f));
    float i2 = fastrcp(fmaxf(s2, 1e-9f));
    float i3 = fastrcp(fmaxf(s3, 1e-9f));
    alph[wv][lane] = make_float4(a0 * i0, a1 * i1, a2 * i2, a3 * i3);
    srcb[wv][lane] = sv;   // same-wave producer/consumer, no barrier
  }

  // ---- phase 2: gather, half-wave = one edge, 4 dims (8B) per lane ----
  int half = lane >> 5, l5 = lane & 31;
  int d0 = l5 * 4;
  float acc[4][4] = {};   // [head][dim]

#define PR(I)                                                                  \
  {                                                                            \
    int e = (I) + half;                                                        \
    float4 a4 = alph[wv][e];                                                   \
    int s = srcb[wv][e];                                                       \
    uint2 w = *reinterpret_cast<const uint2*>(&featsb[(size_t)s * 128 + d0]);  \
    __hip_bfloat162 u0 = *reinterpret_cast<__hip_bfloat162*>(&w.x);            \
    __hip_bfloat162 u1 = *reinterpret_cast<__hip_bfloat162*>(&w.y);            \
    float2 fA = __bfloat1622float2(u0);                                        \
    float2 fB = __bfloat1622float2(u1);                                        \
    acc[0][0] += a4.x * fA.x; acc[0][1] += a4.x * fA.y;                        \
    acc[0][2] += a4.x * fB.x; acc[0][3] += a4.x * fB.y;                        \
    acc[1][0] += a4.y * fA.x; acc[1][1] += a4.y * fA.y;                        \
    acc[1][2] += a4.y * fB.x; acc[1][3] += a4.y * fB.y;                        \
    acc[2][0] += a4.z * fA.x; acc[2][1] += a4.z * fA.y;                        \
    acc[2][2] += a4.z * fB.x; acc[2][3] += a4.z * fB.y;                        \
    acc[3][0] += a4.w * fA.x; acc[3][1] += a4.w * fA.y;                        \
    acc[3][2] += a4.w * fB.x; acc[3][3] += a4.w * fB.y;                        \
  }

  int i = 0;
  for (; i + 3 < c; i += 4) { PR(i) PR(i + 2) }
  for (; i < c; i += 2) PR(i)
#undef PR

  // combine the two halves (each lane then holds the full sum for its 4 dims)
#pragma unroll
  for (int h = 0; h < 4; ++h)
#pragma unroll
    for (int j = 0; j < 4; ++j) acc[h][j] += __shfl_xor(acc[h][j], 32);

  // store: half 0 writes heads 0-1, half 1 writes heads 2-3 (8B each)
#pragma unroll
  for (int hh = 0; hh < 2; ++hh) {
    int h = half * 2 + hh;
    __hip_bfloat162 o0 = __float22bfloat162_rn(make_float2(acc[h][0], acc[h][1]));
    __hip_bfloat162 o1 = __float22bfloat162_rn(make_float2(acc[h][2], acc[h][3]));
    uint2 pk;
    pk.x = *reinterpret_cast<unsigned int*>(&o0);
    pk.y = *reinterpret_cast<unsigned int*>(&o1);
    *reinterpret_cast<uint2*>(&aggb[(size_t)n * HD + h * 128 + d0]) = pk;
  }
}

// ---------------- h1 GEMM + MFMA 12-dot epilogue ----------------------------
// R6 structure (zero shuffles, MFMA second GEMM, atomic combine into compact
// elq/er2), plus: each block now processes TWO row-tiles with Bs/Vc staged
// ONCE (halves the 40MB B-restage L2 traffic; 1256 -> 628 blocks).
__global__ __launch_bounds__(256) void h1_gemm_kernel(
    const __hip_bfloat16* __restrict__ A,    // aggb [MPAD][512] bf16
    const __hip_bfloat16* __restrict__ Bt,   // W1t  [512][128] bf16
    const __hip_bfloat16* __restrict__ vcombh, // [4][16][128] bf16 pre-swizzled
    const float* __restrict__ b1,            // [512]
    float* __restrict__ elq,                 // [NN][8] el+q
    float* __restrict__ er2) {               // [NN][4]
  __shared__ short AsH[64 * 128];           // 16 KB: agg tile, then h1 tile
  __shared__ short Bs[128 * 128];           // 32 KB: W1t head-slice
  __shared__ short Vc[16 * 128];            // 4 KB: vcombh head-slice
  int t = threadIdx.x;
  int lane = t & 63, wave = t >> 6;
  int head = blockIdx.y;
  int nloc = lane & 15, quad = lane >> 4;

  // ---- stage B + Vc once per block ----
#pragma unroll
  for (int p = 0; p < 8; ++p) {             // B: 128 rows x 16 slots
    int fbase = p * 256 + wave * 64;
    int f = fbase + lane;
    int row = f >> 4, slot = f & 15;
    int ss = slot ^ (row & 7);
    gload16(Bt + (size_t)(head * 128 + row) * 128 + ss * 8, Bs + fbase * 8);
  }
  {
    int fbase = wave * 64;                  // Vc: pre-swizzled in global
    gload16(vcombh + head * 2048 + (size_t)(fbase + lane) * 8, Vc + fbase * 8);
  }

  for (int it = 0; it < 2; ++it) {
    int rowBase = (blockIdx.x * 2 + it) * 64;
    if (it) __syncthreads();   // all waves done reading AsH from prior tile

    // ---- stage A tile ----
#pragma unroll
    for (int p = 0; p < 4; ++p) {           // A: 64 rows x 16 slots
      int fbase = p * 256 + wave * 64;
      int f = fbase + lane;
      int row = f >> 4, slot = f & 15;
      int ss = slot ^ (row & 7);
      gload16(A + (size_t)(rowBase + row) * HD + head * 128 + ss * 8,
              AsH + fbase * 8);
    }
    __syncthreads();   // staging (incl. B/Vc on first iter) complete

    // ---- first GEMM: D[col][node], wave owns 16 nodes x all 128 cols ----
    f32x4 acc[8];
#pragma unroll
    for (int i = 0; i < 8; ++i) acc[i] = (f32x4){0.f, 0.f, 0.f, 0.f};
#pragma unroll
    for (int c = 0; c < 4; ++c) {
      int arow = wave * 16 + nloc;
      short8 bfr = *(const short8*)&AsH[arow * 128 +
                                        (((c << 2) + quad) ^ (arow & 7)) * 8];
#pragma unroll
      for (int i = 0; i < 8; ++i) {
        int brow = i * 16 + nloc;
        short8 af = *(const short8*)&Bs[brow * 128 +
                                        (((c << 2) + quad) ^ (brow & 7)) * 8];
        acc[i] = __builtin_amdgcn_mfma_f32_16x16x32_bf16(af, bfr, acc[i],
                                                         0, 0, 0);
      }
    }

    // ---- elu(acc + b1) -> bf16 -> H1 (overlay on AsH, wave-local rows) ----
    int node = wave * 16 + nloc;
#pragma unroll
    for (int i = 0; i < 8; ++i) {
      float4 b4 = *reinterpret_cast<const float4*>(
          &b1[head * 128 + i * 16 + quad * 4]);
      float e0 = fast_elu(acc[i][0] + b4.x);
      float e1 = fast_elu(acc[i][1] + b4.y);
      float e2 = fast_elu(acc[i][2] + b4.z);
      float e3 = fast_elu(acc[i][3] + b4.w);
      __hip_bfloat162 p0 = __float22bfloat162_rn(make_float2(e0, e1));
      __hip_bfloat162 p1 = __float22bfloat162_rn(make_float2(e2, e3));
      uint2 pk;
      pk.x = *reinterpret_cast<unsigned int*>(&p0);
      pk.y = *reinterpret_cast<unsigned int*>(&p1);
      int slot = i * 2 + (quad >> 1);
      int sub = quad & 1;
      int sl = slot ^ (node & 7);
      *reinterpret_cast<uint2*>(&AsH[node * 128 + sl * 8 + sub * 4]) = pk;
    }

    // ---- second GEMM: D2[vv][node] = Vc[16x128] . h1[128x16] ----
    f32x4 acc2 = (f32x4){0.f, 0.f, 0.f, 0.f};
#pragma unroll
    for (int c = 0; c < 4; ++c) {
      short8 a2 = *(const short8*)&Vc[nloc * 128 +
                                      (((c << 2) + quad) ^ (nloc & 7)) * 8];
      short8 b2v = *(const short8*)&AsH[node * 128 +
                                        (((c << 2) + quad) ^ (node & 7)) * 8];
      acc2 = __builtin_amdgcn_mfma_f32_16x16x32_bf16(a2, b2v, acc2, 0, 0, 0);
    }

    // vv = quad*4 + r, node = lane&15; atomic k-slice combine (compact)
    int gn = rowBase + node;
    if (gn < NN) {
      if (quad == 0) {
#pragma unroll
        for (int r = 0; r < 4; ++r)
          atomicAdd(&elq[(size_t)gn * 8 + r], acc2[r]);
      } else if (quad == 1) {
#pragma unroll
        for (int r = 0; r < 4; ++r)
          atomicAdd(&er2[(size_t)gn * 4 + r], acc2[r]);
      } else if (quad == 2) {
#pragma unroll
        for (int r = 0; r < 4; ++r)
          atomicAdd(&elq[(size_t)gn * 8 + 4 + r], acc2[r]);
      }
    }
  }
}

// ---------------- layer-2 attention + readout dot (R6-identical) ------------
__global__ __launch_bounds__(256) void attn_q_kernel(
    const int* __restrict__ src_perm,
    const int* __restrict__ cnt,
    const float* __restrict__ elq,          // [NN][8]
    const float* __restrict__ er2,          // [NN][4]
    float* __restrict__ partials) {         // [256]
  __shared__ float blk[4];
  int wv = __builtin_amdgcn_readfirstlane((int)(threadIdx.x >> 6));
  int n = blockIdx.x * 4 + wv;
  int lane = threadIdx.x & 63;
  int c = min(cnt[n], SLOTS);
  float4 er4 = *reinterpret_cast<const float4*>(&er2[n * 4]);
  float a0 = 0.f, a1 = 0.f, a2 = 0.f, a3 = 0.f;
  float4 q4 = make_float4(0.f, 0.f, 0.f, 0.f);
  if (lane < c) {
    int s = src_perm[n * SLOTS + lane];
    float4 e4 = *reinterpret_cast<const float4*>(&elq[(size_t)s * 8]);
    q4 = *reinterpret_cast<const float4*>(&elq[(size_t)s * 8 + 4]);
    float x0 = e4.x + er4.x, x1 = e4.y + er4.y;
    float x2 = e4.z + er4.z, x3 = e4.w + er4.w;
    x0 = (x0 > 0.f) ? x0 : NEG_SLOPE * x0;
    x1 = (x1 > 0.f) ? x1 : NEG_SLOPE * x1;
    x2 = (x2 > 0.f) ? x2 : NEG_SLOPE * x2;
    x3 = (x3 > 0.f) ? x3 : NEG_SLOPE * x3;
    a0 = __expf(x0); a1 = __expf(x1); a2 = __expf(x2); a3 = __expf(x3);
  }
  float s0 = a0, s1 = a1, s2 = a2, s3 = a3;
#pragma unroll
  for (int off = 1; off < 64; off <<= 1) {
    s0 += __shfl_xor(s0, off);
    s1 += __shfl_xor(s1, off);
    s2 += __shfl_xor(s2, off);
    s3 += __shfl_xor(s3, off);
  }
  float p = 0.f;
  if (lane < c) {
    p = (a0 * fastrcp(fmaxf(s0, 1e-9f))) * q4.x +
        (a1 * fastrcp(fmaxf(s1, 1e-9f))) * q4.y +
        (a2 * fastrcp(fmaxf(s2, 1e-9f))) * q4.z +
        (a3 * fastrcp(fmaxf(s3, 1e-9f))) * q4.w;
  }
#pragma unroll
  for (int off = 32; off > 0; off >>= 1) p += __shfl_down(p, off);
  if (lane == 0) blk[wv] = p;
  __syncthreads();
  if (threadIdx.x == 0) {
    atomicAdd(&partials[blockIdx.x & 255], blk[0] + blk[1] + blk[2] + blk[3]);
  }
}

// ---------------- final: out = 0.25*(sum partials + NN*b2.Wr_rep) + NN*br ----
__global__ __launch_bounds__(512) void final_kernel(
    const float* __restrict__ partials, const float* __restrict__ b2,
    const float* __restrict__ Wr, const float* __restrict__ br,
    float* __restrict__ out) {
  __shared__ float tmp[512];
  int t = threadIdx.x;
  float sum = (t < 256) ? partials[t] : 0.f;
  sum += (float)NN * b2[t] * Wr[t & 127];
  tmp[t] = sum;
  __syncthreads();
  for (int off = 256; off > 0; off >>= 1) {
    if (t < off) tmp[t] += tmp[t + off];
    __syncthreads();
  }
  if (t == 0) out[0] = 0.25f * tmp[0] + (float)NN * br[0];
}

// ---------------- launch ----------------
extern "C" void kernel_launch(void* const* d_in, const int* in_sizes, int n_in,
                              void* d_out, int out_size, void* d_ws, size_t ws_size,
                              hipStream_t stream) {
  const float* feats = (const float*)d_in[0];
  const int* src = (const int*)d_in[1];
  const int* dst = (const int*)d_in[2];
  const float* W1 = (const float*)d_in[3];
  const float* al1 = (const float*)d_in[4];
  const float* ar1 = (const float*)d_in[5];
  const float* b1 = (const float*)d_in[6];
  const float* W2 = (const float*)d_in[7];
  const float* al2 = (const float*)d_in[8];
  const float* ar2 = (const float*)d_in[9];
  const float* b2 = (const float*)d_in[10];
  const float* Wr = (const float*)d_in[11];
  const float* br = (const float*)d_in[12];
  float* out = (float*)d_out;

  // workspace layout (~33 MB); all section sizes multiples of 16 B
  __hip_bfloat16* featsb = (__hip_bfloat16*)d_ws;               // NN*128 bf16
  __hip_bfloat16* aggb = featsb + (size_t)NN * 128;             // MPAD*512 bf16
  __hip_bfloat16* W1t = aggb + (size_t)MPAD * HD;               // 512*128 bf16
  __hip_bfloat16* vcombh = W1t + 512 * 128;                     // 4*16*128 bf16
  float* wl1t = (float*)(vcombh + 4 * 16 * 128);                // 128*4 f32
  float* wr1t = wl1t + 512;                                     // 128*4 f32
  float* el1 = wr1t + 512;                                      // NN*4
  float* er1 = el1 + (size_t)NN * NHEAD;                        // NN*4
  float* elq = er1 + (size_t)NN * NHEAD;                        // NN*8
  float* er2 = elq + (size_t)NN * 8;                            // NN*4
  float* partials = er2 + (size_t)NN * NHEAD;                   // 256
  int* cnt = (int*)(partials + 256);                            // NN
  int* src_perm = cnt + NN;                                     // NN*SLOTS

  // prep: cnt zero + feats->bf16 + W1^T + vcombh + wl1t/wr1t + zeros
  prep_kernel<<<(S6 + 255) / 256, 256, 0, stream>>>(
      feats, W1, W2, al1, ar1, al2, ar2, Wr, featsb, W1t, vcombh, wl1t, wr1t,
      elq, partials, cnt);

  // CSR fill + layer-1 logits (2 nodes/wave, 8B loads)
  fill_logits_kernel<<<NN / 8, 256, 0, stream>>>(
      src, dst, cnt, src_perm, featsb, wl1t, wr1t, el1, er1);

  // layer-1 attn + FEATS aggregation (2 edges/wave-iter, 8B loads)
  gather_kernel<<<NN / 4, 256, 0, stream>>>(featsb, cnt, src_perm, el1, er1,
                                            aggb);

  // agg @ W1 -> h1 (in-LDS) -> atomic combine into compact elq/er2
  dim3 h1grid(MPAD / 128, NHEAD);
  h1_gemm_kernel<<<h1grid, 256, 0, stream>>>(aggb, W1t, vcombh, b1, elq, er2);

  // layer-2 attention + readout dot; spread partials then tiny final reduce
  attn_q_kernel<<<NN / 4, 256, 0, stream>>>(src_perm, cnt, elq, er2, partials);
  final_kernel<<<1, 512, 0, stream>>>(partials, b2, Wr, br, out);
}